// Round 15
// baseline (573.475 us; speedup 1.0000x reference)
//
#include <hip/hip_runtime.h>
#include <hip/hip_bf16.h>

#define SEQ   2048
#define BATCH 256
#define HDIM  64
#define GDIM  256   // 4*H

typedef __attribute__((ext_vector_type(8))) short bf16x8;  // 8 bf16 = 4 VGPR
typedef __attribute__((ext_vector_type(4))) float f32x4;

static __device__ __forceinline__ unsigned short f2bf(float f) {
    return __builtin_bit_cast(unsigned short, __float2bfloat16(f));
}

// MFMA LSTM — r9 skeleton (champion 514us), ONE isolated change (from r10's
// bundle): the hidden_seq global store is DEFERRED one step and issued at the
// top of the next iteration, in the post-barrier region where it overlaps the
// ds_read latency shadow instead of extending the serial pre-barrier segment.
// All arithmetic bit-identical to r9: 4 parallel depth-2 mfma_16x16x32_bf16
// chains (bias in C), xb post-add, saturating sigmoid/tanh, bf16 h via LDS.
// One WG per batch element, 4 waves; wave w owns units [16w,16w+16).
// D layout (validated r8): col=lane&15, rows replicated -> lane reads acc[0].
// Barrier = sched_barrier-fenced raw lgkmcnt(0)+s_barrier (r9's exact form).
__global__ __launch_bounds__(256, 1) void lstm_mfma8(
    const float* __restrict__ xin,   // [S,B,2]
    const float* __restrict__ Wih,   // [2,256]
    const float* __restrict__ Whh,   // [64,256]
    const float* __restrict__ bih,   // [256]
    const float* __restrict__ bhh,   // [256]
    float* __restrict__ out)         // fp32: hidden_seq [S,B,64] | h [B,64] | c [B,64]
{
    const int b   = blockIdx.x;
    const int tid = threadIdx.x;
    const int w   = tid >> 6;    // wave 0..3
    const int l   = tid & 63;    // lane
    const int lg  = l >> 4;      // k-group 0..3
    const int lc  = l & 15;      // tile column
    const int u   = 16 * w + lc; // hidden unit this lane handles

    __shared__ __align__(16) unsigned short v_hi[2][HDIM];  // h bf16, dbuf
    __shared__ float2 xf[SEQ];                              // staged x pairs (fp32)

    // ---- stage x for this batch column ----
    const float2* x2 = reinterpret_cast<const float2*>(xin);
    #pragma unroll
    for (int r = 0; r < SEQ / 256; ++r) {
        int s = r * 256 + tid;
        xf[s] = x2[(size_t)s * BATCH + b];
    }

    // ---- persistent weight fragments (B operand): gate g = 64t + 16w + lc,
    //      k = 32*kc + 8*lg + e ----
    bf16x8 wf[4][2];
    f32x4  biasv[4];
    float  wx0[4], wx1[4];
    #pragma unroll
    for (int t = 0; t < 4; ++t) {
        const int g = 64 * t + 16 * w + lc;
        #pragma unroll
        for (int kc = 0; kc < 2; ++kc) {
            bf16x8 f;
            #pragma unroll
            for (int e = 0; e < 8; ++e) {
                int k = 32 * kc + 8 * lg + e;
                f[e] = (short)f2bf(Whh[k * GDIM + g]);
            }
            wf[t][kc] = f;
        }
        wx0[t] = Wih[0 * GDIM + g];
        wx1[t] = Wih[1 * GDIM + g];
        const float bb = bih[g] + bhh[g];
        biasv[t] = (f32x4){bb, bb, bb, bb};
    }

    if (tid < HDIM) { v_hi[0][tid] = 0; v_hi[1][tid] = 0; }
    float c_state = 0.0f, hval = 0.0f, h_prev = 0.0f;
    __syncthreads();

    const float L2E = 1.44269504088896340736f;

    for (int s = 0; s < SEQ; ++s) {
        const int buf = s & 1;

        // deferred store of previous step's h — post-barrier region, overlaps
        // the ds_read latency shadow (fire-and-forget; never read in-kernel)
        if (l < 16 && s > 0)
            out[(size_t)(s - 1) * (BATCH * HDIM) + (size_t)b * HDIM + u] = h_prev;

        // A fragments: h vector, identical across the 16 replica rows
        bf16x8 ah0 = *reinterpret_cast<const bf16x8*>(&v_hi[buf][8 * lg]);       // k 0..31
        bf16x8 ah1 = *reinterpret_cast<const bf16x8*>(&v_hi[buf][32 + 8 * lg]);  // k 32..63

        // x contribution in fp32 on VALU (overlaps the ds_reads)
        const float2 xv = xf[s];
        float xb[4];
        #pragma unroll
        for (int t = 0; t < 4; ++t)
            xb[t] = wx0[t] * xv.x + wx1[t] * xv.y;

        // 4 parallel depth-2 MFMA chains (bias in C)
        f32x4 acc[4];
        #pragma unroll
        for (int t = 0; t < 4; ++t)
            acc[t] = __builtin_amdgcn_mfma_f32_16x16x32_bf16(ah0, wf[t][0], biasv[t], 0, 0, 0);
        #pragma unroll
        for (int t = 0; t < 4; ++t)
            acc[t] = __builtin_amdgcn_mfma_f32_16x16x32_bf16(ah1, wf[t][1], acc[t], 0, 0, 0);

        const float ip = acc[0][0] + xb[0];
        const float fp = acc[1][0] + xb[1];
        const float gp = acc[2][0] + xb[2];
        const float op = acc[3][0] + xb[3];

        // activations (in-lane): i,f,o sigmoid; g tanh (saturating forms)
        const float iv = __builtin_amdgcn_rcpf(1.0f + __builtin_amdgcn_exp2f(-L2E * ip));
        const float fv = __builtin_amdgcn_rcpf(1.0f + __builtin_amdgcn_exp2f(-L2E * fp));
        const float gv = 2.0f * __builtin_amdgcn_rcpf(1.0f + __builtin_amdgcn_exp2f(-2.0f * L2E * gp)) - 1.0f;
        const float ov = __builtin_amdgcn_rcpf(1.0f + __builtin_amdgcn_exp2f(-L2E * op));

        c_state = fv * c_state + iv * gv;
        const float tc = 2.0f * __builtin_amdgcn_rcpf(1.0f + __builtin_amdgcn_exp2f(-2.0f * L2E * c_state)) - 1.0f;
        hval = ov * tc;

        if (l < 16)
            v_hi[buf ^ 1][u] = f2bf(hval);   // feed next step (bf16)
        h_prev = hval;

        // LDS-only barrier (r9's exact fenced form)
        __builtin_amdgcn_sched_barrier(0);
        asm volatile("s_waitcnt lgkmcnt(0)\n\ts_barrier" ::: "memory");
        __builtin_amdgcn_sched_barrier(0);
    }

    // final stores: last hidden_seq row + h, c (fp32)
    if (l < 16) {
        const size_t HO = (size_t)SEQ * BATCH * HDIM;
        out[(size_t)(SEQ - 1) * (BATCH * HDIM) + (size_t)b * HDIM + u] = h_prev;
        out[HO + (size_t)b * HDIM + u] = h_prev;
        out[HO + (size_t)BATCH * HDIM + (size_t)b * HDIM + u] = c_state;
    }
}

extern "C" void kernel_launch(void* const* d_in, const int* in_sizes, int n_in,
                              void* d_out, int out_size, void* d_ws, size_t ws_size,
                              hipStream_t stream) {
    const float* xin = (const float*)d_in[0];
    const float* Wih = (const float*)d_in[1];
    const float* Whh = (const float*)d_in[2];
    const float* bih = (const float*)d_in[3];
    const float* bhh = (const float*)d_in[4];
    float* out = (float*)d_out;

    lstm_mfma8<<<BATCH, 256, 0, stream>>>(xin, Wih, Whh, bih, bhh, out);
}

// Round 16
// 512.203 us; speedup vs baseline: 1.1196x; 1.1196x over previous
//
#include <hip/hip_runtime.h>
#include <hip/hip_bf16.h>

#define SEQ   2048
#define BATCH 256
#define HDIM  64
#define GDIM  256   // 4*H

typedef __attribute__((ext_vector_type(8))) short bf16x8;  // 8 bf16 = 4 VGPR
typedef __attribute__((ext_vector_type(4))) float f32x4;

static __device__ __forceinline__ unsigned short f2bf(float f) {
    return __builtin_bit_cast(unsigned short, __float2bfloat16(f));
}

// MFMA LSTM, lean chain — CHAMPION configuration (r9, 514us), restored
// byte-for-byte after six single-variable probes (r11-r15) all regressed:
//   de-chained MFMAs +56us, C-operand folding +36us, fence removal +16us,
//   issue reorder +11us, deferred store +59us.
// One workgroup per batch element, 4 waves; wave w owns units [16w,16w+16).
// Per step: 8 mfma_16x16x32_bf16 in 4 parallel depth-2 chains (bias in C),
// h fed back as plain bf16 via LDS; x@Wih on VALU in fp32 (overlaps ds_reads);
// saturating sigmoid/tanh via exp2/rcp.
// D layout (validated r8): col=lane&15, rows replicated -> lane reads acc[0].
// Barrier = sched_barrier-fenced raw lgkmcnt(0)+s_barrier: orders the LDS
// h-exchange WITHOUT draining the fire-and-forget global stores (vmcnt).
// Per-step chain ~600 cyc: MFMA pipe ~150 + trans chain ~150 + LDS+barrier
// ~200 + VALU ~100 (overlapped) — structural latency floor of this
// decomposition; alternatives (1-wave, 32x32 MFMA, batched-M) compute worse.
__global__ __launch_bounds__(256, 1) void lstm_mfma_final(
    const float* __restrict__ xin,   // [S,B,2]
    const float* __restrict__ Wih,   // [2,256]
    const float* __restrict__ Whh,   // [64,256]
    const float* __restrict__ bih,   // [256]
    const float* __restrict__ bhh,   // [256]
    float* __restrict__ out)         // fp32: hidden_seq [S,B,64] | h [B,64] | c [B,64]
{
    const int b   = blockIdx.x;
    const int tid = threadIdx.x;
    const int w   = tid >> 6;    // wave 0..3
    const int l   = tid & 63;    // lane
    const int lg  = l >> 4;      // k-group 0..3
    const int lc  = l & 15;      // tile column
    const int u   = 16 * w + lc; // hidden unit this lane handles

    __shared__ __align__(16) unsigned short v_hi[2][HDIM];  // h bf16, dbuf
    __shared__ float2 xf[SEQ];                              // staged x pairs (fp32)

    // ---- stage x for this batch column ----
    const float2* x2 = reinterpret_cast<const float2*>(xin);
    #pragma unroll
    for (int r = 0; r < SEQ / 256; ++r) {
        int s = r * 256 + tid;
        xf[s] = x2[(size_t)s * BATCH + b];
    }

    // ---- persistent weight fragments (B operand): gate g = 64t + 16w + lc,
    //      k = 32*kc + 8*lg + e ----
    bf16x8 wf[4][2];
    f32x4  biasv[4];
    float  wx0[4], wx1[4];
    #pragma unroll
    for (int t = 0; t < 4; ++t) {
        const int g = 64 * t + 16 * w + lc;
        #pragma unroll
        for (int kc = 0; kc < 2; ++kc) {
            bf16x8 f;
            #pragma unroll
            for (int e = 0; e < 8; ++e) {
                int k = 32 * kc + 8 * lg + e;
                f[e] = (short)f2bf(Whh[k * GDIM + g]);
            }
            wf[t][kc] = f;
        }
        wx0[t] = Wih[0 * GDIM + g];
        wx1[t] = Wih[1 * GDIM + g];
        const float bb = bih[g] + bhh[g];
        biasv[t] = (f32x4){bb, bb, bb, bb};
    }

    if (tid < HDIM) { v_hi[0][tid] = 0; v_hi[1][tid] = 0; }
    float c_state = 0.0f, hval = 0.0f;
    __syncthreads();

    const float L2E = 1.44269504088896340736f;

    for (int s = 0; s < SEQ; ++s) {
        const int buf = s & 1;
        // A fragments: h vector, identical across the 16 replica rows
        bf16x8 ah0 = *reinterpret_cast<const bf16x8*>(&v_hi[buf][8 * lg]);       // k 0..31
        bf16x8 ah1 = *reinterpret_cast<const bf16x8*>(&v_hi[buf][32 + 8 * lg]);  // k 32..63

        // x contribution in fp32 on VALU (overlaps the ds_reads)
        const float2 xv = xf[s];
        float xb[4];
        #pragma unroll
        for (int t = 0; t < 4; ++t)
            xb[t] = wx0[t] * xv.x + wx1[t] * xv.y;

        // 4 parallel depth-2 MFMA chains (bias in C)
        f32x4 acc[4];
        #pragma unroll
        for (int t = 0; t < 4; ++t)
            acc[t] = __builtin_amdgcn_mfma_f32_16x16x32_bf16(ah0, wf[t][0], biasv[t], 0, 0, 0);
        #pragma unroll
        for (int t = 0; t < 4; ++t)
            acc[t] = __builtin_amdgcn_mfma_f32_16x16x32_bf16(ah1, wf[t][1], acc[t], 0, 0, 0);

        const float ip = acc[0][0] + xb[0];
        const float fp = acc[1][0] + xb[1];
        const float gp = acc[2][0] + xb[2];
        const float op = acc[3][0] + xb[3];

        // activations (in-lane): i,f,o sigmoid; g tanh (saturating forms)
        const float iv = __builtin_amdgcn_rcpf(1.0f + __builtin_amdgcn_exp2f(-L2E * ip));
        const float fv = __builtin_amdgcn_rcpf(1.0f + __builtin_amdgcn_exp2f(-L2E * fp));
        const float gv = 2.0f * __builtin_amdgcn_rcpf(1.0f + __builtin_amdgcn_exp2f(-2.0f * L2E * gp)) - 1.0f;
        const float ov = __builtin_amdgcn_rcpf(1.0f + __builtin_amdgcn_exp2f(-L2E * op));

        c_state = fv * c_state + iv * gv;
        const float tc = 2.0f * __builtin_amdgcn_rcpf(1.0f + __builtin_amdgcn_exp2f(-2.0f * L2E * c_state)) - 1.0f;
        hval = ov * tc;

        if (l < 16) {
            v_hi[buf ^ 1][u] = f2bf(hval);   // feed next step (bf16)
            out[(size_t)s * (BATCH * HDIM) + (size_t)b * HDIM + u] = hval;  // fire-and-forget
        }

        // LDS-only barrier: order h exchange WITHOUT draining global stores
        __builtin_amdgcn_sched_barrier(0);
        asm volatile("s_waitcnt lgkmcnt(0)\n\ts_barrier" ::: "memory");
        __builtin_amdgcn_sched_barrier(0);
    }

    // final h, c (fp32)
    if (l < 16) {
        const size_t HO = (size_t)SEQ * BATCH * HDIM;
        out[HO + (size_t)b * HDIM + u] = hval;
        out[HO + (size_t)BATCH * HDIM + (size_t)b * HDIM + u] = c_state;
    }
}

extern "C" void kernel_launch(void* const* d_in, const int* in_sizes, int n_in,
                              void* d_out, int out_size, void* d_ws, size_t ws_size,
                              hipStream_t stream) {
    const float* xin = (const float*)d_in[0];
    const float* Wih = (const float*)d_in[1];
    const float* Whh = (const float*)d_in[2];
    const float* bih = (const float*)d_in[3];
    const float* bhh = (const float*)d_in[4];
    float* out = (float*)d_out;

    lstm_mfma_final<<<BATCH, 256, 0, stream>>>(xin, Wih, Whh, bih, bhh, out);
}